// Round 9
// baseline (58395.929 us; speedup 1.0000x reference)
//
#include <hip/hip_runtime.h>
#include <hip/hip_fp16.h>

#define EPSF 1e-8f
#define SCOPE_AGT __HIP_MEMORY_SCOPE_AGENT

// T=512 B=64 IN=256 OUT=256 H=512 N=2048 C=64 R=4
// 256 blocks x 1024 threads (cooperative, 1/CU), 4 blocks/batch (R5 skeleton).
// mem in registers; per-batch monotone barriers; relaxed agent atomics for
// small payloads only. NEW: x-GEMV moved into the A-barrier shadow, h-GEMV
// hides the B-wait, software-pipelined weight loads, 11 syncthreads/step,
// fp16 projection weights.

typedef _Float16 h2_t __attribute__((ext_vector_type(2)));

struct P9 {
  const unsigned* W2h;  // [4 chunk][416 rp][512 cc] u32 = half2{row 2rp,2rp+1}
  const _Float16* Wkg;  // [512 row][128 cl] key64|gen64
  const _Float16* Wy;   // [512 row][256 col]
  const float* b_lstm;  // 2048
  const float* b_out;   // 256
  const float* b_key;   // 64
  const float* W_beta;  // 512
  const float* b_beta;  // 1
  const float* b_gen;   // 64
  const float* xs;      // [512][64][256]
  float* hbuf;          // [64 b][512]
  float* AccP;          // [64 b][4 chunk][64 c]
  float* ZP;            // [64 b][4]
  float* S2P;           // [64 b][4]
  unsigned* ctr;        // [64 b][32]
  float* out;           // [512][64][256] + loss at 8388608
};

__device__ __forceinline__ float sigm(float x) { return 1.f / (1.f + __expf(-x)); }
__device__ __forceinline__ float aload(const float* p) {
  return __hip_atomic_load(p, __ATOMIC_RELAXED, SCOPE_AGT);
}
__device__ __forceinline__ void astore(float* p, float v) {
  __hip_atomic_store(p, v, __ATOMIC_RELAXED, SCOPE_AGT);
}
__device__ __forceinline__ h2_t u2h(unsigned u) {
  union { unsigned u; h2_t h; } x; x.u = u; return x.h;
}

#if defined(__has_builtin)
#if __has_builtin(__builtin_amdgcn_fdot2)
#define HAVE_FDOT2 1
#endif
#endif

__device__ __forceinline__ float dot2acc(h2_t a, h2_t b, float c) {
#ifdef HAVE_FDOT2
  return __builtin_amdgcn_fdot2(a, b, c, false);
#else
  return fmaf((float)a.x, (float)b.x, fmaf((float)a.y, (float)b.y, c));
#endif
}

// double-buffered GEMV over NRP rowpairs (stride 512 u32 per rowpair)
template <int NRP>
__device__ __forceinline__ void gemv_db(const unsigned* wp, const _Float16* ip, float4& acc) {
  uint4 wb[2][4];
#pragma unroll
  for (int k = 0; k < 4; ++k) wb[0][k] = *(const uint4*)(wp + (size_t)k * 512);
  constexpr int NB = NRP / 4;
#pragma unroll
  for (int blkI = 0; blkI < NB; ++blkI) {
    const int cur = blkI & 1;
    if (blkI + 1 < NB) {
#pragma unroll
      for (int k = 0; k < 4; ++k)
        wb[cur ^ 1][k] = *(const uint4*)(wp + (size_t)((blkI + 1) * 4 + k) * 512);
    }
#pragma unroll
    for (int k = 0; k < 4; ++k) {
      const h2_t v = *(const h2_t*)(ip + (blkI * 4 + k) * 2);
      const uint4 w = wb[cur][k];
      acc.x = dot2acc(u2h(w.x), v, acc.x);
      acc.y = dot2acc(u2h(w.y), v, acc.y);
      acc.z = dot2acc(u2h(w.z), v, acc.z);
      acc.w = dot2acc(u2h(w.w), v, acc.w);
    }
  }
}

__global__ void __launch_bounds__(1024, 4) dnc_b9(P9 P) {
  const int tid   = threadIdx.x;
  const int bid   = blockIdx.x;
  const int chunk = (bid >> 1) & 3;
  const int b     = ((bid >> 3) << 1) | (bid & 1);
  const int lane  = tid & 63;
  const int wv    = tid >> 6;
  const int sgrp  = lane >> 4;
  const int c4    = lane & 15;

  __shared__ _Float16 s_ih[832];   // fp16 [x(256)|h(512)|r(64)]
  __shared__ float s_h[512];
  __shared__ float s_gates[512];
  __shared__ float s_c[128];
  __shared__ float s_part[4096];
  __shared__ float s_e[512];
  __shared__ float s_key[64], s_kprev[64], s_genv[64];
  __shared__ float s_wred[32];
  __shared__ float s_bred[8];
  __shared__ float s_scal[4];      // 0:invZ_prev 1:S2_prev 2:beta 3:||key||

  unsigned* ctr = P.ctr + b * 32;

  float4 mreg[8];
  float  sden[8];
#pragma unroll
  for (int i = 0; i < 8; ++i) mreg[i] = make_float4(0.f, 0.f, 0.f, 0.f);

  for (int i = 256 + tid; i < 832; i += 1024) s_ih[i] = (_Float16)0.f;
  if (tid < 512) { s_h[tid] = 0.f; s_e[tid] = 0.f; }
  if (tid < 128) {
    s_c[tid] = 0.f;
    const float2 xv0 = ((const float2*)P.xs)[(size_t)b * 128 + tid];
    h2_t hv; hv.x = (_Float16)xv0.x; hv.y = (_Float16)xv0.y;
    *(h2_t*)&s_ih[tid * 2] = hv;
  }
  if (tid < 64) s_kprev[tid] = 0.f;
  if (tid == 0) { s_scal[0] = 0.f; s_scal[1] = 0.f; }
  float lossacc = 0.f;
  __syncthreads();

  const int q  = tid >> 7;         // 0..7
  const int cg = tid & 127;        // 4 gate-cols
  const unsigned* wbase = P.W2h + (size_t)chunk * 212992 + (cg << 2);
  const unsigned* wpx = wbase + (size_t)(q * 16) * 512;          // x rows: rp [q*16,+16)
  const unsigned* wph = wbase + (size_t)(128 + q * 32) * 512;    // h rows: rp [128+q*32,+32)
  const unsigned* wpr = wbase + (size_t)(384 + q * 4) * 512;     // r rows: rp [384+q*4,+4)
  const _Float16* ipx = s_ih + q * 32;
  const _Float16* iph = s_ih + 256 + q * 64;
  const _Float16* ipr = s_ih + 768 + q * 8;

  // prologue: x-GEMV for t=0
  float4 acc = make_float4(0.f, 0.f, 0.f, 0.f);
  gemv_db<16>(wpx, ipx, acc);

  for (int t = 0; t < 512; ++t) {
    // (0) prefetch x_{t+1} into registers (overlaps h-GEMV)
    float2 xv = make_float2(0.f, 0.f);
    if (tid < 128 && t < 511)
      xv = ((const float2*)P.xs)[((size_t)(t + 1) * 64 + b) * 128 + tid];

    // (1) h-GEMV (hides B-wait)
    gemv_db<32>(wph, iph, acc);

    // (2) wait barrier B_{t-1}
    if (t > 0 && tid == 0) {
      while (__hip_atomic_load(ctr, __ATOMIC_RELAXED, SCOPE_AGT) < 8u * (unsigned)t)
        __builtin_amdgcn_s_sleep(1);
    }
    __syncthreads();                                             // S1

    // (3) r finalize (per-thread Z/S2, no broadcast sync) + x_{t+1} -> LDS
    if (t > 0 && tid <= 64) {
      const float* zp = P.ZP + b * 4;
      const float* sp = P.S2P + b * 4;
      const float Z  = aload(zp) + aload(zp + 1) + aload(zp + 2) + aload(zp + 3);
      const float S2 = aload(sp) + aload(sp + 1) + aload(sp + 2) + aload(sp + 3);
      const float iZ = 1.f / Z;
      if (tid < 64) {
        const float* ap = P.AccP + b * 256 + tid;
        const float a0 = aload(ap) + aload(ap + 64) + aload(ap + 128) + aload(ap + 192);
        const float r = iZ * a0 + S2 * iZ * iZ * s_kprev[tid];
        s_ih[768 + tid] = (_Float16)r;
      } else {
        s_scal[0] = iZ; s_scal[1] = S2;                          // for G1 shadow
      }
    }
    if (tid < 128 && t < 511) {
      h2_t hv; hv.x = (_Float16)xv.x; hv.y = (_Float16)xv.y;
      *(h2_t*)&s_ih[tid * 2] = hv;
    }
    __syncthreads();                                             // S2

    // (4) r-GEMV + store gate partials
    {
#pragma unroll
      for (int k = 0; k < 4; ++k) {
        const uint4 w = *(const uint4*)(wpr + (size_t)k * 512);
        const h2_t v = *(const h2_t*)(ipr + k * 2);
        acc.x = dot2acc(u2h(w.x), v, acc.x);
        acc.y = dot2acc(u2h(w.y), v, acc.y);
        acc.z = dot2acc(u2h(w.z), v, acc.z);
        acc.w = dot2acc(u2h(w.w), v, acc.w);
      }
      *(float4*)&s_part[(q << 9) + (cg << 2)] = acc;
    }
    __syncthreads();                                             // S3

    // (5) gates reduce
    if (tid < 512) {
      s_gates[tid] = s_part[tid]        + s_part[512 + tid]  + s_part[1024 + tid] + s_part[1536 + tid]
                   + s_part[2048 + tid] + s_part[2560 + tid] + s_part[3072 + tid] + s_part[3584 + tid];
    }
    __syncthreads();                                             // S4

    // (6) LSTM -> h_t (own 128 j), publish
    if (tid < 128) {
      const int jl = tid, cb = chunk * 128 + jl;
      const float gi = s_gates[jl * 4 + 0] + P.b_lstm[cb];
      const float gf = s_gates[jl * 4 + 1] + P.b_lstm[512 + cb];
      const float gg = s_gates[jl * 4 + 2] + P.b_lstm[1024 + cb];
      const float go = s_gates[jl * 4 + 3] + P.b_lstm[1536 + cb];
      const float cn = sigm(gf) * s_c[jl] + sigm(gi) * tanhf(gg);
      s_c[jl] = cn;
      const float hn = sigm(go) * tanhf(cn);
      s_h[cb] = hn;
      s_ih[256 + cb] = (_Float16)hn;
      astore(P.hbuf + b * 512 + cb, hn);
    }
    __syncthreads();                                             // S5 (drains h stores)
    if (tid == 0) __hip_atomic_fetch_add(ctr, 1u, __ATOMIC_RELEASE, SCOPE_AGT);  // post A

    // (7) A-shadow: pending rank-1 update + slot norms + x-GEMV for t+1
    {
      const float invZp = s_scal[0];
      const float4 kp4 = ((const float4*)s_kprev)[c4];
      const int nbase = (wv * 4 + sgrp) * 8;
#pragma unroll
      for (int it = 0; it < 8; ++it) {
        float4 m4 = mreg[it];
        const float wpv = s_e[nbase + it] * invZp;               // w_{t-1}[n] (0 at t=0)
        m4.x = fmaf(wpv, kp4.x, m4.x); m4.y = fmaf(wpv, kp4.y, m4.y);
        m4.z = fmaf(wpv, kp4.z, m4.z); m4.w = fmaf(wpv, kp4.w, m4.w);
        float ssq = m4.x * m4.x + m4.y * m4.y + m4.z * m4.z + m4.w * m4.w;
#pragma unroll
        for (int off = 1; off < 16; off <<= 1) ssq += __shfl_xor(ssq, off);
        sden[it] = fmaxf(sqrtf(ssq), EPSF);
        mreg[it] = m4;
      }
    }
    float4 accN = make_float4(0.f, 0.f, 0.f, 0.f);
    if (t < 511) gemv_db<16>(wpx, ipx, accN);

    // (8) wait A
    if (tid == 0) {
      while (__hip_atomic_load(ctr, __ATOMIC_RELAXED, SCOPE_AGT) < 8u * (unsigned)t + 4u)
        __builtin_amdgcn_s_sleep(1);
    }
    __syncthreads();                                             // S6

    // (9) peers' h
    if (tid < 384) {
      const int pc = tid >> 7;
      const int pcc = pc + (pc >= chunk ? 1 : 0);
      const int jl = tid & 127;
      const float hv = aload(P.hbuf + b * 512 + pcc * 128 + jl);
      s_h[pcc * 128 + jl] = hv;
      s_ih[256 + pcc * 128 + jl] = (_Float16)hv;
    }
    __syncthreads();                                             // S7

    // (10) projection partials (fp16 weights) from full h
    {
      {  // key|gen: 8 rowgroups x 128 cols (64 rows each)
        const int rg = tid >> 7, cl = tid & 127;
        const _Float16* wp = P.Wkg + cl;
        const float* hh = s_h + rg * 64;
        float a = 0.f;
#pragma unroll 8
        for (int r = 0; r < 64; ++r) a = fmaf(hh[r], (float)wp[(size_t)(rg * 64 + r) * 128], a);
        s_part[rg * 128 + cl] = a;
      }
      {  // y own 64-col slice: 16 rowgroups x 64 cols (32 rows each)
        const int rg2 = tid >> 6, c6 = tid & 63;
        const _Float16* wp = P.Wy + chunk * 64 + c6;
        const float* hh = s_h + rg2 * 32;
        float a = 0.f;
#pragma unroll 8
        for (int r = 0; r < 32; ++r) a = fmaf(hh[r], (float)wp[(size_t)(rg2 * 32 + r) * 256], a);
        s_part[1024 + (rg2 << 6) + c6] = a;
      }
      {  // beta partials
        float pb = (tid < 512) ? s_h[tid] * P.W_beta[tid] : 0.f;
#pragma unroll
        for (int off = 32; off; off >>= 1) pb += __shfl_down(pb, off);
        if (tid < 512 && lane == 0) s_bred[wv] = pb;
      }
    }
    __syncthreads();                                             // S8

    // (11) reduces: key + ||key|| (wave0), gen (wave1), y out, softplus
    if (tid < 64) {
      float v = 0.f;
#pragma unroll
      for (int k = 0; k < 8; ++k) v += s_part[k * 128 + tid];
      v += P.b_key[tid];
      s_key[tid] = v;
      float sq = v * v;
#pragma unroll
      for (int off = 32; off; off >>= 1) sq += __shfl_down(sq, off);
      if (lane == 0) s_scal[3] = fmaxf(sqrtf(sq), EPSF);
    } else if (tid < 128) {
      const int c = tid - 64;
      float v = 0.f;
#pragma unroll
      for (int k = 0; k < 8; ++k) v += s_part[k * 128 + 64 + c];
      s_genv[c] = v + P.b_gen[c];
    } else if (tid < 192) {
      const int col = tid - 128, oc = chunk * 64 + col;
      float v = 0.f;
#pragma unroll
      for (int k = 0; k < 16; ++k) v += s_part[1024 + (k << 6) + col];
      P.out[((size_t)t * 64 + b) * 256 + oc] = v + P.b_out[oc];
    } else if (tid == 192) {
      float s = P.b_beta[0];
#pragma unroll
      for (int k = 0; k < 8; ++k) s += s_bred[k];
      s_scal[2] = (s > 20.f) ? s : log1pf(__expf(s));            // softplus
    }
    __syncthreads();                                             // S9

    // (13) sim/exp/acc on updated register mem
    {
      const float beta = s_scal[2], kn = s_scal[3];
      const float4 kk = ((const float4*)s_key)[c4];
      float Zp = 0.f, S2p = 0.f;
      float4 acc4 = make_float4(0.f, 0.f, 0.f, 0.f);
      const int nbase = (wv * 4 + sgrp) * 8;
#pragma unroll
      for (int it = 0; it < 8; ++it) {
        const float4 m4 = mreg[it];
        float num = m4.x * kk.x + m4.y * kk.y + m4.z * kk.z + m4.w * kk.w;
#pragma unroll
        for (int off = 1; off < 16; off <<= 1) num += __shfl_xor(num, off);
        const float e = __expf(beta * (num / (sden[it] * kn)));
        if (c4 == 0) { s_e[nbase + it] = e; Zp += e; S2p += e * e; }
        acc4.x = fmaf(e, m4.x, acc4.x); acc4.y = fmaf(e, m4.y, acc4.y);
        acc4.z = fmaf(e, m4.z, acc4.z); acc4.w = fmaf(e, m4.w, acc4.w);
      }
#pragma unroll
      for (int off = 32; off; off >>= 1) { Zp += __shfl_down(Zp, off); S2p += __shfl_down(S2p, off); }
      if (lane == 0) { s_wred[wv] = Zp; s_wred[16 + wv] = S2p; }
#pragma unroll
      for (int off = 16; off < 64; off <<= 1) {
        acc4.x += __shfl_down(acc4.x, off); acc4.y += __shfl_down(acc4.y, off);
        acc4.z += __shfl_down(acc4.z, off); acc4.w += __shfl_down(acc4.w, off);
      }
      if (lane < 16) ((float4*)s_part)[wv * 16 + lane] = acc4;
    }
    __syncthreads();                                             // S10

    // (14) publish Acc/Z/S2 + kprev + loss
    if (tid < 64) {
      float a = 0.f;
#pragma unroll
      for (int w = 0; w < 16; ++w) a += s_part[w * 64 + tid];
      astore(P.AccP + (b * 4 + chunk) * 64 + tid, a);
      s_kprev[tid] = s_key[tid];
    } else if (tid == 64) {
      float Z = 0.f, S2 = 0.f;
#pragma unroll
      for (int k = 0; k < 16; ++k) { Z += s_wred[k]; S2 += s_wred[16 + k]; }
      astore(P.ZP + b * 4 + chunk, Z);
      astore(P.S2P + b * 4 + chunk, S2);
    } else if (wv == 2 && chunk == 0) {
      const float d = s_key[lane] - s_genv[lane];
      float ds = d * d;
#pragma unroll
      for (int off = 32; off; off >>= 1) ds += __shfl_down(ds, off);
      if (lane == 0) lossacc += ds;                              // tid 128
    }
    __syncthreads();                                             // S11 (drains stores)
    if (tid == 0) __hip_atomic_fetch_add(ctr, 1u, __ATOMIC_RELEASE, SCOPE_AGT);  // post B

    acc = accN;
  }

  if (chunk == 0 && tid == 128) atomicAdd(P.out + 8388608, lossacc * (1.f / 4096.f));
}

//============================ prep kernels ============================
// W2h[chunk][rp][cc] = half2{W[2rp][col], W[2rp+1][col]}, col = g*512+chunk*128+jl,
// cc = jl*4+g. rows [0,256)=W_ih(x), [256,768)=W_hh, [768,832)=W_ih read-rows folded (R=4).
__global__ void build_w2h(const float* __restrict__ W_ih, const float* __restrict__ W_hh,
                          unsigned* __restrict__ W2h) {
  const int id = blockIdx.x * 256 + threadIdx.x;   // over 4*416*512
  if (id >= 851968) return;
  const int chunk = id / 212992;
  const int rem   = id % 212992;
  const int rp    = rem >> 9;
  const int cc    = rem & 511;
  const int jl = cc >> 2, g = cc & 3;
  const int col = g * 512 + chunk * 128 + jl;
  float v[2];
#pragma unroll
  for (int k = 0; k < 2; ++k) {
    const int row = rp * 2 + k;
    if (row < 256)      v[k] = W_ih[(size_t)row * 2048 + col];
    else if (row < 768) v[k] = W_hh[(size_t)(row - 256) * 2048 + col];
    else {
      const float* p0 = W_ih + (size_t)(256 + (row - 768) * 4) * 2048 + col;
      v[k] = p0[0] + p0[2048] + p0[4096] + p0[6144];
    }
  }
  const __half2 h2v = __floats2half2_rn(v[0], v[1]);
  W2h[id] = *(const unsigned*)&h2v;
}

__global__ void build_wkg(const float* __restrict__ W_key, const float* __restrict__ W_gen,
                          _Float16* __restrict__ Wkg) {
  const int id = blockIdx.x * 256 + threadIdx.x;   // 512*128
  if (id >= 65536) return;
  const int row = id >> 7, cl = id & 127;
  const float v = (cl < 64) ? W_key[(size_t)row * 64 + cl] : W_gen[(size_t)row * 64 + cl - 64];
  Wkg[id] = (_Float16)v;
}

__global__ void build_wy(const float* __restrict__ W_out, _Float16* __restrict__ Wy) {
  const int id = blockIdx.x * 256 + threadIdx.x;   // 512*256
  if (id >= 131072) return;
  Wy[id] = (_Float16)W_out[id];
}

extern "C" void kernel_launch(void* const* d_in, const int* in_sizes, int n_in,
                              void* d_out, int out_size, void* d_ws, size_t ws_size,
                              hipStream_t stream) {
  const float* xs     = (const float*)d_in[0];
  const float* W_ih   = (const float*)d_in[1];
  const float* W_hh   = (const float*)d_in[2];
  const float* b_lstm = (const float*)d_in[3];
  const float* W_out  = (const float*)d_in[4];
  const float* b_out  = (const float*)d_in[5];
  const float* W_key  = (const float*)d_in[6];
  const float* b_key  = (const float*)d_in[7];
  const float* W_beta = (const float*)d_in[8];
  const float* b_beta = (const float*)d_in[9];
  const float* W_gen  = (const float*)d_in[10];
  const float* b_gen  = (const float*)d_in[11];
  float* out = (float*)d_out;

  float* ws = (float*)d_ws;
  unsigned* W2h = (unsigned*)ws;                // 851,968 u32
  _Float16* Wkg = (_Float16*)(ws + 851968);     // 65,536 h (32,768 f)
  _Float16* Wy  = (_Float16*)(ws + 884736);     // 131,072 h (65,536 f)
  float* hbuf  = ws + 950272;                   // 32,768
  float* AccP  = hbuf + 32768;                  // 16,384
  float* ZP    = AccP + 16384;                  // 256
  float* S2P   = ZP + 256;                      // 256
  unsigned* ctr = (unsigned*)(S2P + 256);       // 2,048 u32

  hipMemsetAsync(ctr, 0, 2048 * sizeof(unsigned), stream);
  hipMemsetAsync(out + 8388608, 0, sizeof(float), stream);

  build_w2h<<<dim3(3328), dim3(256), 0, stream>>>(W_ih, W_hh, W2h);
  build_wkg<<<dim3(256),  dim3(256), 0, stream>>>(W_key, W_gen, Wkg);
  build_wy<<<dim3(512),   dim3(256), 0, stream>>>(W_out, Wy);

  P9 prm;
  prm.W2h = W2h; prm.Wkg = Wkg; prm.Wy = Wy;
  prm.b_lstm = b_lstm; prm.b_out = b_out; prm.b_key = b_key;
  prm.W_beta = W_beta; prm.b_beta = b_beta; prm.b_gen = b_gen;
  prm.xs = xs;
  prm.hbuf = hbuf; prm.AccP = AccP; prm.ZP = ZP; prm.S2P = S2P;
  prm.ctr = ctr; prm.out = out;

  void* kargs[] = { &prm };
  hipLaunchCooperativeKernel(reinterpret_cast<void*>(&dnc_b9),
                             dim3(256), dim3(1024), kargs, 0, stream);
}

// Round 10
// 13206.287 us; speedup vs baseline: 4.4218x; 4.4218x over previous
//
#include <hip/hip_runtime.h>
#include <hip/hip_fp16.h>

#define EPSF 1e-8f
#define SCOPE_AGT __HIP_MEMORY_SCOPE_AGENT

// T=512 B=64 IN=256 OUT=256 H=512 N=2048 C=64 R=4
// 256 blocks x 1024 threads (1/CU, cooperative co-residency), 4 blocks/batch.
// EXACT round-4 structure (best: 13.37 ms): mem in registers (32 VGPR),
// fence-free small-payload agent atomics, h/partial exchange at barrier A,
// deferred rank-1 update in the barrier shadow. Only change vs R4:
// projection weights (W_key|W_gen -> Wkg, W_out -> Wy) pre-packed fp16,
// halving the E2 projection L2 stream. No register/sync/live-range changes.

typedef _Float16 h2_t __attribute__((ext_vector_type(2)));

struct P4 {
  const unsigned* W2h;  // [4 chunk][416 rowpairs][512 cc] packed half2
  const _Float16* Wkg;  // [512 row][128 cl]  cl: key64|gen64
  const _Float16* Wy;   // [512 row][256 col]
  const float* b_lstm;  // 2048
  const float* b_out;   // 256
  const float* b_key;   // 64
  const float* W_beta;  // 512
  const float* b_beta;  // 1
  const float* b_gen;   // 64
  const float* xs;      // [512][64][256]
  float* hbuf;          // [64][512]
  float* keyP;          // [64][4][64]
  float* genP;          // [64][4][64]
  float* yP;            // [64][4][256]
  float* betaP;         // [64][4]
  float* AccP;          // [64][4][64]
  float* ZP;            // [64][4]
  float* S2P;           // [64][4]
  unsigned* ctr;        // [64][32]
  float* out;           // [512][64][256] + loss at 8388608
};

__device__ __forceinline__ float sigm(float x) { return 1.f / (1.f + __expf(-x)); }
__device__ __forceinline__ float aload(const float* p) {
  return __hip_atomic_load(p, __ATOMIC_RELAXED, SCOPE_AGT);
}
__device__ __forceinline__ void astore(float* p, float v) {
  __hip_atomic_store(p, v, __ATOMIC_RELAXED, SCOPE_AGT);
}

__global__ void __launch_bounds__(1024, 4) dnc_b4(P4 P) {
  const int tid   = threadIdx.x;
  const int bid   = blockIdx.x;
  const int chunk = (bid >> 1) & 3;                 // XCD(bid%8) hosts one chunk value
  const int b     = ((bid >> 3) << 1) | (bid & 1);
  const int lane  = tid & 63;
  const int wv    = tid >> 6;
  const int sgrp  = lane >> 4;
  const int c4    = lane & 15;

  __shared__ float s_inp[832];     // [x(256) | h(512) | r(64)]
  __shared__ float s_gates[512];
  __shared__ float s_c[128];
  __shared__ float s_part[4096];
  __shared__ float s_e[512];
  __shared__ float s_key[64], s_kprev[64], s_genv[64];
  __shared__ float s_wred[32];
  __shared__ float s_scal[4];      // 0:invZ_prev 1:S2_prev 2:beta 3:||key||

  unsigned* ctr = P.ctr + b * 32;

  float4 mreg[8];                  // own 512 slots
  float  sden[8];
#pragma unroll
  for (int i = 0; i < 8; ++i) mreg[i] = make_float4(0.f, 0.f, 0.f, 0.f);

  for (int i = 256 + tid; i < 832; i += 1024) s_inp[i] = 0.f;
  if (tid < 128) s_c[tid] = 0.f;
  if (tid < 512) s_e[tid] = 0.f;
  if (tid < 64)  s_kprev[tid] = 0.f;
  float lossacc = 0.f;
  __syncthreads();

  const int q  = tid >> 7;         // 0..7 rowpair-chunk
  const int cg = tid & 127;        // col-group (4 cols)
  const unsigned* wbase = P.W2h + (size_t)chunk * 212992 + (cg << 2);

  for (int t = 0; t < 512; ++t) {
    // ---- load x_t
    if (tid < 128)
      ((float2*)s_inp)[tid] = ((const float2*)P.xs)[((size_t)t * 64 + b) * 128 + tid];
    __syncthreads();

    // ---- GEMV part 1: rowpairs [q*48,+48) (x+h rows; no barrier needed)
    float4 acc = make_float4(0.f, 0.f, 0.f, 0.f);
    {
      const unsigned* wp = wbase + (size_t)(q * 48) * 512;
      const float* ip = s_inp + q * 96;
#pragma unroll 4
      for (int r = 0; r < 48; ++r) {
        const uint4 w = *(const uint4*)(wp + (size_t)r * 512);
        const float2 v = *(const float2*)(ip + r * 2);
        const __half2* h2 = (const __half2*)&w;
        const float2 f0 = __half22float2(h2[0]), f1 = __half22float2(h2[1]);
        const float2 f2 = __half22float2(h2[2]), f3 = __half22float2(h2[3]);
        acc.x = fmaf(v.x, f0.x, fmaf(v.y, f0.y, acc.x));
        acc.y = fmaf(v.x, f1.x, fmaf(v.y, f1.y, acc.y));
        acc.z = fmaf(v.x, f2.x, fmaf(v.y, f2.y, acc.z));
        acc.w = fmaf(v.x, f3.x, fmaf(v.y, f3.y, acc.w));
      }
    }

    // ---- C: wait barrier B_{t-1}; finalize r_{t-1}
    if (t > 0) {
      if (tid == 0) {
        while (__hip_atomic_load(ctr, __ATOMIC_RELAXED, SCOPE_AGT) < 8u * (unsigned)t)
          __builtin_amdgcn_s_sleep(1);
      }
      __syncthreads();
      float a0 = 0.f, a1 = 0.f, a2 = 0.f, a3 = 0.f;
      if (tid < 64) {
        const float* ap = P.AccP + b * 256 + tid;
        a0 = aload(ap); a1 = aload(ap + 64); a2 = aload(ap + 128); a3 = aload(ap + 192);
      } else if (tid == 64) {
        const float* zp = P.ZP + b * 4;
        const float* sp = P.S2P + b * 4;
        const float Z  = aload(zp) + aload(zp + 1) + aload(zp + 2) + aload(zp + 3);
        const float S2 = aload(sp) + aload(sp + 1) + aload(sp + 2) + aload(sp + 3);
        s_scal[0] = 1.f / Z;  s_scal[1] = S2;
      }
      __syncthreads();
      if (tid < 64) {
        const float iZ = s_scal[0];
        s_inp[768 + tid] = iZ * ((a0 + a1 + a2 + a3) + s_scal[1] * iZ * s_kprev[tid]);
      }
      __syncthreads();
    } else {
      if (tid == 64) { s_scal[0] = 0.f; s_scal[1] = 0.f; }  // r pre-zeroed
      __syncthreads();
    }

    // ---- GEMV part 2: rowpairs [384+q*4,+4) (r rows)
    {
      const unsigned* wp = wbase + (size_t)(384 + q * 4) * 512;
      const float* ip = s_inp + 768 + q * 8;
#pragma unroll
      for (int r = 0; r < 4; ++r) {
        const uint4 w = *(const uint4*)(wp + (size_t)r * 512);
        const float2 v = *(const float2*)(ip + r * 2);
        const __half2* h2 = (const __half2*)&w;
        const float2 f0 = __half22float2(h2[0]), f1 = __half22float2(h2[1]);
        const float2 f2 = __half22float2(h2[2]), f3 = __half22float2(h2[3]);
        acc.x = fmaf(v.x, f0.x, fmaf(v.y, f0.y, acc.x));
        acc.y = fmaf(v.x, f1.x, fmaf(v.y, f1.y, acc.y));
        acc.z = fmaf(v.x, f2.x, fmaf(v.y, f2.y, acc.z));
        acc.w = fmaf(v.x, f3.x, fmaf(v.y, f3.y, acc.w));
      }
    }
    *(float4*)&s_part[(q << 9) + (cg << 2)] = acc;
    __syncthreads();

    // ---- gates reduce + LSTM -> h_t (own 128 j), publish h chunk
    if (tid < 512) {
      s_gates[tid] = s_part[tid]        + s_part[512 + tid]  + s_part[1024 + tid] + s_part[1536 + tid]
                   + s_part[2048 + tid] + s_part[2560 + tid] + s_part[3072 + tid] + s_part[3584 + tid];
    }
    __syncthreads();
    if (tid < 128) {
      const int jl = tid, cb = chunk * 128 + jl;
      const float gi = s_gates[jl * 4 + 0] + P.b_lstm[cb];
      const float gf = s_gates[jl * 4 + 1] + P.b_lstm[512 + cb];
      const float gg = s_gates[jl * 4 + 2] + P.b_lstm[1024 + cb];
      const float go = s_gates[jl * 4 + 3] + P.b_lstm[1536 + cb];
      const float cn = sigm(gf) * s_c[jl] + sigm(gi) * tanhf(gg);
      s_c[jl] = cn;
      const float hn = sigm(go) * tanhf(cn);
      s_inp[256 + cb] = hn;
      astore(P.hbuf + b * 512 + cb, hn);
    }
    __syncthreads();

    // ---- E2: own-h-row projection partials (rows [chunk*128,+128)), fp16 weights
    {
      const float* h = s_inp + 256 + chunk * 128;
      {  // keyP (tid<512) / genP (tid>=512): 8 rowgroups x 64 cols, 16 rows each
        const int isg = tid >> 9, rg = (tid >> 6) & 7, c = tid & 63;
        const _Float16* wp2 = P.Wkg + (size_t)(chunk * 128 + rg * 16) * 128 + isg * 64 + c;
        const float* hh = h + rg * 16;
        float a2 = 0.f;
#pragma unroll
        for (int r2 = 0; r2 < 16; ++r2) a2 = fmaf(hh[r2], (float)wp2[(size_t)r2 * 128], a2);
        s_part[tid] = a2;
      }
      {  // yP: 4 rowgroups x 256 cols, 32 rows each
        const int rg = tid >> 8, col = tid & 255;
        const _Float16* wp2 = P.Wy + (size_t)(chunk * 128 + rg * 32) * 256 + col;
        const float* hh = h + rg * 32;
        float a2 = 0.f;
#pragma unroll 8
        for (int r2 = 0; r2 < 32; ++r2) a2 = fmaf(hh[r2], (float)wp2[(size_t)r2 * 256], a2);
        s_part[1024 + (rg << 8) + col] = a2;
      }
      {  // betaP: own 128 rows (waves 0,1)
        float pb = (tid < 128) ? h[tid] * P.W_beta[chunk * 128 + tid] : 0.f;
#pragma unroll
        for (int off = 32; off; off >>= 1) pb += __shfl_down(pb, off);
        if (tid < 128 && lane == 0) s_wred[wv] = pb;
      }
    }
    __syncthreads();
    // ---- E3: reduce + publish partials
    if (tid < 64) {
      float v = 0.f;
#pragma unroll
      for (int k = 0; k < 8; ++k) v += s_part[k * 64 + tid];
      astore(P.keyP + (b * 4 + chunk) * 64 + tid, v);
    } else if (tid < 128) {
      const int c = tid - 64;
      float v = 0.f;
#pragma unroll
      for (int k = 0; k < 8; ++k) v += s_part[512 + k * 64 + c];
      astore(P.genP + (b * 4 + chunk) * 64 + c, v);
    } else if (tid < 384) {
      const int col = tid - 128;
      astore(P.yP + (b * 4 + chunk) * 256 + col,
             s_part[1024 + col] + s_part[1280 + col] + s_part[1536 + col] + s_part[1792 + col]);
    } else if (tid == 384) {
      astore(P.betaP + b * 4 + chunk, s_wred[0] + s_wred[1]);
    }
    __syncthreads();                              // drains stores (vmcnt) before post
    if (tid == 0) __hip_atomic_fetch_add(ctr, 1u, __ATOMIC_RELEASE, SCOPE_AGT);  // post A

    // ---- G1 (in barrier-A shadow): apply pending rank-1 update; slot norms
    {
      const float invZp = s_scal[0];
      const float4 kp4 = ((const float4*)s_kprev)[c4];
      const int nbase = (wv * 4 + sgrp) * 8;
#pragma unroll
      for (int it = 0; it < 8; ++it) {
        float4 m4 = mreg[it];
        const float wpv = s_e[nbase + it] * invZp;   // w_{t-1}[n]  (0 at t=0)
        m4.x = fmaf(wpv, kp4.x, m4.x); m4.y = fmaf(wpv, kp4.y, m4.y);
        m4.z = fmaf(wpv, kp4.z, m4.z); m4.w = fmaf(wpv, kp4.w, m4.w);
        float ssq = m4.x * m4.x + m4.y * m4.y + m4.z * m4.z + m4.w * m4.w;
#pragma unroll
        for (int off = 1; off < 16; off <<= 1) ssq += __shfl_xor(ssq, off);
        sden[it] = fmaxf(sqrtf(ssq), EPSF);
        mreg[it] = m4;
      }
    }

    // ---- F: wait A; assemble key/gen/y/beta; fetch peers' h
    if (tid == 0) {
      while (__hip_atomic_load(ctr, __ATOMIC_RELAXED, SCOPE_AGT) < 8u * (unsigned)t + 4u)
        __builtin_amdgcn_s_sleep(1);
    }
    __syncthreads();
    if (tid < 64) {
      const float* kp = P.keyP + b * 256 + tid;
      s_key[tid] = aload(kp) + aload(kp + 64) + aload(kp + 128) + aload(kp + 192) + P.b_key[tid];
    } else if (tid < 128) {
      const int c = tid - 64;
      const float* gp = P.genP + b * 256 + c;
      s_genv[c] = aload(gp) + aload(gp + 64) + aload(gp + 128) + aload(gp + 192) + P.b_gen[c];
    } else if (tid < 192) {
      const int col = tid - 128, oc = chunk * 64 + col;
      const float* yp = P.yP + b * 1024 + oc;
      P.out[((size_t)t * 64 + b) * 256 + oc] =
          aload(yp) + aload(yp + 256) + aload(yp + 512) + aload(yp + 768) + P.b_out[oc];
    } else if (tid == 192) {
      const float* bp = P.betaP + b * 4;
      const float s = aload(bp) + aload(bp + 1) + aload(bp + 2) + aload(bp + 3) + P.b_beta[0];
      s_scal[2] = (s > 20.f) ? s : log1pf(__expf(s));   // softplus
    } else if (tid >= 256 && tid < 640) {
      const int i = tid - 256;
      const int pc = i >> 7;
      const int pcc = pc + (pc >= chunk ? 1 : 0);       // peer chunks
      const int jl = i & 127;
      s_inp[256 + pcc * 128 + jl] = aload(P.hbuf + b * 512 + pcc * 128 + jl);
    }
    __syncthreads();
    if (wv == 0) {
      const float kv = s_key[lane];
      float sq = kv * kv;
#pragma unroll
      for (int off = 32; off; off >>= 1) sq += __shfl_down(sq, off);
      if (lane == 0) s_scal[3] = fmaxf(sqrtf(sq), EPSF);
    } else if (wv == 1 && chunk == 0) {
      const float d = s_key[lane] - s_genv[lane];
      float ds = d * d;
#pragma unroll
      for (int off = 32; off; off >>= 1) ds += __shfl_down(ds, off);
      if (lane == 0) lossacc += ds;                      // tid 64
    }
    __syncthreads();

    // ---- G2: sim/exp/acc on updated mem (registers)
    {
      const float beta = s_scal[2], kn = s_scal[3];
      const float4 kk = ((const float4*)s_key)[c4];
      float Zp = 0.f, S2p = 0.f;
      float4 acc4 = make_float4(0.f, 0.f, 0.f, 0.f);
      const int nbase = (wv * 4 + sgrp) * 8;
#pragma unroll
      for (int it = 0; it < 8; ++it) {
        const float4 m4 = mreg[it];
        float num = m4.x * kk.x + m4.y * kk.y + m4.z * kk.z + m4.w * kk.w;
#pragma unroll
        for (int off = 1; off < 16; off <<= 1) num += __shfl_xor(num, off);
        const float e = __expf(beta * (num / (sden[it] * kn)));
        if (c4 == 0) { s_e[nbase + it] = e; Zp += e; S2p += e * e; }
        acc4.x = fmaf(e, m4.x, acc4.x); acc4.y = fmaf(e, m4.y, acc4.y);
        acc4.z = fmaf(e, m4.z, acc4.z); acc4.w = fmaf(e, m4.w, acc4.w);
      }
#pragma unroll
      for (int off = 32; off; off >>= 1) { Zp += __shfl_down(Zp, off); S2p += __shfl_down(S2p, off); }
      if (lane == 0) { s_wred[wv] = Zp; s_wred[16 + wv] = S2p; }
#pragma unroll
      for (int off = 16; off < 64; off <<= 1) {
        acc4.x += __shfl_down(acc4.x, off); acc4.y += __shfl_down(acc4.y, off);
        acc4.z += __shfl_down(acc4.z, off); acc4.w += __shfl_down(acc4.w, off);
      }
      if (lane < 16) ((float4*)s_part)[wv * 16 + lane] = acc4;
    }
    __syncthreads();
    if (tid < 64) {
      float a = 0.f;
#pragma unroll
      for (int w = 0; w < 16; ++w) a += s_part[w * 64 + tid];
      astore(P.AccP + (b * 4 + chunk) * 64 + tid, a);
      s_kprev[tid] = s_key[tid];
    } else if (tid == 64) {
      float Z = 0.f, S2 = 0.f;
#pragma unroll
      for (int k = 0; k < 16; ++k) { Z += s_wred[k]; S2 += s_wred[16 + k]; }
      astore(P.ZP + b * 4 + chunk, Z);
      astore(P.S2P + b * 4 + chunk, S2);
    }
    __syncthreads();                              // drains stores before post
    if (tid == 0) __hip_atomic_fetch_add(ctr, 1u, __ATOMIC_RELEASE, SCOPE_AGT);  // post B
  }

  if (chunk == 0 && tid == 64) atomicAdd(P.out + 8388608, lossacc * (1.f / 4096.f));
}

// W2h[chunk][rp][cc] = half2{W[2rp][col], W[2rp+1][col]}, col = g*512 + chunk*128 + jl,
// cc = jl*4+g. rows [0,256)=W_ih(x), [256,768)=W_hh, [768,832)=W_ih read-rows folded (R=4).
__global__ void build_w2h(const float* __restrict__ W_ih, const float* __restrict__ W_hh,
                          unsigned* __restrict__ W2h) {
  const int id = blockIdx.x * 256 + threadIdx.x;   // over 4*416*512
  if (id >= 851968) return;
  const int chunk = id / 212992;
  const int rem   = id % 212992;
  const int rp    = rem >> 9;
  const int cc    = rem & 511;
  const int jl = cc >> 2, g = cc & 3;
  const int col = g * 512 + chunk * 128 + jl;
  float v[2];
#pragma unroll
  for (int k = 0; k < 2; ++k) {
    const int row = rp * 2 + k;
    if (row < 256)      v[k] = W_ih[(size_t)row * 2048 + col];
    else if (row < 768) v[k] = W_hh[(size_t)(row - 256) * 2048 + col];
    else {
      const float* p0 = W_ih + (size_t)(256 + (row - 768) * 4) * 2048 + col;
      v[k] = p0[0] + p0[2048] + p0[4096] + p0[6144];
    }
  }
  const __half2 h2v = __floats2half2_rn(v[0], v[1]);
  W2h[id] = *(const unsigned*)&h2v;
}

__global__ void build_wkg(const float* __restrict__ W_key, const float* __restrict__ W_gen,
                          _Float16* __restrict__ Wkg) {
  const int id = blockIdx.x * 256 + threadIdx.x;   // 512*128
  if (id >= 65536) return;
  const int row = id >> 7, cl = id & 127;
  const float v = (cl < 64) ? W_key[(size_t)row * 64 + cl] : W_gen[(size_t)row * 64 + cl - 64];
  Wkg[id] = (_Float16)v;
}

__global__ void build_wy(const float* __restrict__ W_out, _Float16* __restrict__ Wy) {
  const int id = blockIdx.x * 256 + threadIdx.x;   // 512*256
  if (id >= 131072) return;
  Wy[id] = (_Float16)W_out[id];
}

extern "C" void kernel_launch(void* const* d_in, const int* in_sizes, int n_in,
                              void* d_out, int out_size, void* d_ws, size_t ws_size,
                              hipStream_t stream) {
  const float* xs     = (const float*)d_in[0];
  const float* W_ih   = (const float*)d_in[1];
  const float* W_hh   = (const float*)d_in[2];
  const float* b_lstm = (const float*)d_in[3];
  const float* W_out  = (const float*)d_in[4];
  const float* b_out  = (const float*)d_in[5];
  const float* W_key  = (const float*)d_in[6];
  const float* b_key  = (const float*)d_in[7];
  const float* W_beta = (const float*)d_in[8];
  const float* b_beta = (const float*)d_in[9];
  const float* W_gen  = (const float*)d_in[10];
  const float* b_gen  = (const float*)d_in[11];
  float* out = (float*)d_out;

  float* ws = (float*)d_ws;
  unsigned* W2h = (unsigned*)ws;           //   851,968 u32
  _Float16* Wkg = (_Float16*)(ws + 851968);//    65,536 h (32,768 f)
  _Float16* Wy  = (_Float16*)(ws + 884736);//   131,072 h (65,536 f)
  float* hbuf  = ws     + 950272;          //    32,768
  float* keyP  = hbuf   + 32768;           //    16,384
  float* genP  = keyP   + 16384;           //    16,384
  float* yP    = genP   + 16384;           //    65,536
  float* betaP = yP     + 65536;           //       256
  float* AccP  = betaP  + 256;             //    16,384
  float* ZP    = AccP   + 16384;           //       256
  float* S2P   = ZP     + 256;             //       256
  unsigned* ctr = (unsigned*)(S2P + 256);  //     2,048 u32

  hipMemsetAsync(ctr, 0, 2048 * sizeof(unsigned), stream);
  hipMemsetAsync(out + 8388608, 0, sizeof(float), stream);

  build_w2h<<<dim3(3328), dim3(256), 0, stream>>>(W_ih, W_hh, W2h);
  build_wkg<<<dim3(256), dim3(256), 0, stream>>>(W_key, W_gen, Wkg);
  build_wy<<<dim3(512),  dim3(256), 0, stream>>>(W_out, Wy);

  P4 prm;
  prm.W2h = W2h; prm.Wkg = Wkg; prm.Wy = Wy;
  prm.b_lstm = b_lstm; prm.b_out = b_out; prm.b_key = b_key;
  prm.W_beta = W_beta; prm.b_beta = b_beta; prm.b_gen = b_gen;
  prm.xs = xs;
  prm.hbuf = hbuf; prm.keyP = keyP; prm.genP = genP; prm.yP = yP; prm.betaP = betaP;
  prm.AccP = AccP; prm.ZP = ZP; prm.S2P = S2P;
  prm.ctr = ctr;  prm.out = out;

  void* kargs[] = { &prm };
  hipLaunchCooperativeKernel(reinterpret_cast<void*>(&dnc_b4),
                             dim3(256), dim3(1024), kargs, 0, stream);
}